// Round 5
// baseline (6057.082 us; speedup 1.0000x reference)
//
#include <hip/hip_runtime.h>

typedef unsigned short u16;
typedef unsigned int u32;
typedef __attribute__((ext_vector_type(8))) short short8;
typedef __attribute__((ext_vector_type(4))) float f32x4;

#define NB 256
#define HID2 2048
#define G4 8192
#define K0 2176
#define K1 4096
#define RS1 4160          // padded row stride (elems) for K1-dim buffers
#define CS 2080           // padded c0 row stride (floats)
#define C1RS (50 * HID2)  // c1 state lives in out_prec slices

__device__ __forceinline__ u16 f2b(float f){
  union { float f; u32 u; } v; v.f = f;
  u32 u = v.u;
  u32 r = (u >> 16) & 1u;
  u = u + 0x7fffu + r;
  return (u16)(u >> 16);
}
__device__ __forceinline__ float b2f(u16 h){
  union { u32 u; float f; } v; v.u = ((u32)h) << 16;
  return v.f;
}
__device__ __forceinline__ float blo(u32 a){
  union { u32 u; float f; } v; v.u = a << 16; return v.f;
}
__device__ __forceinline__ float bhi(u32 a){
  union { u32 u; float f; } v; v.u = a & 0xffff0000u; return v.f;
}
__device__ __forceinline__ float sigm(float x){ return 1.0f/(1.0f + __expf(-x)); }
__device__ __forceinline__ float tanh_f(float x){ return 1.0f - 2.0f/(1.0f + __expf(2.0f*x)); }

__device__ __forceinline__ void gload16(const void* g, void* l){
  __builtin_amdgcn_global_load_lds(
      (const __attribute__((address_space(1))) unsigned int*)g,
      (__attribute__((address_space(3))) unsigned int*)l,
      16, 0, 0);
}

// ---------------- prep kernels ----------------

__global__ void prep_w0(const float* __restrict__ wih, const float* __restrict__ whh,
                        const float* __restrict__ bih, const float* __restrict__ bhh,
                        u16* __restrict__ W0, float* __restrict__ bias0){
  int n = blockIdx.y;
  int k8 = (blockIdx.x * 256 + threadIdx.x) * 8;
  if (k8 >= K0) return;
  int u = ((n >> 6) << 4) | (n & 15);
  int gate = (n >> 4) & 3;
  int r = gate * HID2 + u;
  float v[8];
  if (k8 < 96){
    float4 a = *(const float4*)(wih + (size_t)r * 96 + k8);
    float4 b = *(const float4*)(wih + (size_t)r * 96 + k8 + 4);
    v[0]=a.x; v[1]=a.y; v[2]=a.z; v[3]=a.w; v[4]=b.x; v[5]=b.y; v[6]=b.z; v[7]=b.w;
  } else if (k8 < 128){
    #pragma unroll
    for (int j = 0; j < 8; ++j) v[j] = 0.0f;
  } else {
    float4 a = *(const float4*)(whh + (size_t)r * HID2 + (k8 - 128));
    float4 b = *(const float4*)(whh + (size_t)r * HID2 + (k8 - 128) + 4);
    v[0]=a.x; v[1]=a.y; v[2]=a.z; v[3]=a.w; v[4]=b.x; v[5]=b.y; v[6]=b.z; v[7]=b.w;
  }
  short8 o;
  #pragma unroll
  for (int j = 0; j < 8; ++j) o[j] = (short)f2b(v[j]);
  *(short8*)(W0 + (size_t)n * K0 + k8) = o;
  if (k8 == 0) bias0[n] = bih[r] + bhh[r];
}

__global__ void prep_w1(const float* __restrict__ wih, const float* __restrict__ whh,
                        const float* __restrict__ bih, const float* __restrict__ bhh,
                        u16* __restrict__ W1, float* __restrict__ bias1){
  int n = blockIdx.y;
  int k8 = (blockIdx.x * 256 + threadIdx.x) * 8;
  int u = ((n >> 6) << 4) | (n & 15);
  int gate = (n >> 4) & 3;
  int r = gate * HID2 + u;
  const float* src = (k8 < HID2) ? (wih + (size_t)r * HID2 + k8)
                                 : (whh + (size_t)r * HID2 + (k8 - HID2));
  float4 a = *(const float4*)src;
  float4 b = *(const float4*)(src + 4);
  short8 o;
  o[0]=(short)f2b(a.x); o[1]=(short)f2b(a.y); o[2]=(short)f2b(a.z); o[3]=(short)f2b(a.w);
  o[4]=(short)f2b(b.x); o[5]=(short)f2b(b.y); o[6]=(short)f2b(b.z); o[7]=(short)f2b(b.w);
  *(short8*)(W1 + (size_t)n * RS1 + k8) = o;
  if (k8 == 0) bias1[n] = bih[r] + bhh[r];
}

__global__ void prep_wout(const float* __restrict__ wout, u16* __restrict__ WoTb){
  int id = blockIdx.x * 256 + threadIdx.x;   // 96*2048
  int n = id >> 11, k = id & 2047;
  WoTb[(size_t)n * 2048 + k] = f2b(wout[(size_t)k * 96 + n]);
}

__global__ void prep_state(const float* __restrict__ hs, const float* __restrict__ cs,
                           const float* __restrict__ gts, u16* __restrict__ A0_0,
                           u16* __restrict__ A1_0, float* __restrict__ c0,
                           float* __restrict__ c1prec){
  int id = blockIdx.x * 256 + threadIdx.x;   // 256*512 threads, 4 elems each
  int b = id >> 9;
  int j = (id & 511) << 2;
  const float* hp = hs + (size_t)b * 49 * HID2 + j;
  const float* cp = cs + (size_t)b * 49 * HID2 + j;
  float sh[4] = {0,0,0,0}, sc[4] = {0,0,0,0};
  for (int t = 0; t < 49; ++t){
    float4 hv = *(const float4*)(hp + (size_t)t * HID2);
    float4 cv = *(const float4*)(cp + (size_t)t * HID2);
    sh[0]+=hv.x; sh[1]+=hv.y; sh[2]+=hv.z; sh[3]+=hv.w;
    sc[0]+=cv.x; sc[1]+=cv.y; sc[2]+=cv.z; sc[3]+=cv.w;
  }
  float4 gv = *(const float4*)(gts + (size_t)b * HID2 + j);
  float g[4] = {gv.x, gv.y, gv.z, gv.w};
  #pragma unroll
  for (int q = 0; q < 4; ++q){
    float cm = sc[q] / 49.0f;
    c0[(size_t)b * CS + j + q] = cm;
    c1prec[(size_t)b * C1RS + j + q] = cm;   // out_prec[b][0][:] = c1 init
    A0_0[(size_t)b * K0 + 128 + j + q] = f2b(sh[q] / 49.0f);
    A1_0[(size_t)b * RS1 + HID2 + j + q] = f2b((sh[q] + g[q]) / 50.0f);
  }
}

__global__ void prep_x(const float* __restrict__ p, u16* __restrict__ A0_0,
                       u16* __restrict__ A0_1){
  int id = blockIdx.x * 256 + threadIdx.x;  // 256*128
  int b = id >> 7, j = id & 127;
  u16 v = (j < 96) ? f2b(p[(size_t)b * 96 + j]) : (u16)0;
  A0_0[(size_t)b * K0 + j] = v;
  if (j >= 96) A0_1[(size_t)b * K0 + j] = 0;
}

// ---------------- fused GEMM + LSTM cell ----------------
// gates[m][n] = sum_k A[m][k]*W[n][k] (+bias), then cell epilogue.
// A (small, L2-warm): 3-buffered LDS via global_load_lds, raw s_barrier.
// W (83% of bytes): DIRECT to VGPRs via inline-asm global_load_dwordx4,
// double-buffered wA/wB one K-step ahead — per-warp free-running miss
// streams, decoupled from the barrier (the fill-rate wall of rounds 1-4).
template<int K, int RS>
__global__ __launch_bounds__(256) void gemm_cell(
    const u16* __restrict__ A, const u16* __restrict__ W, const float* __restrict__ bias,
    const float* __restrict__ c_in, int ci_rs, float* __restrict__ c_out, int co_rs,
    u16* __restrict__ h0o, int h0_rs, u16* __restrict__ h1o, int h1_rs)
{
  __shared__ u16 ldsA[3][64 * 64];    // 8KB each, 24KB total
  const int tid = threadIdx.x;
  const int id = blockIdx.x;
  const int bx = ((id & 7) << 3) | ((id >> 3) & 7);
  const int by = id >> 6;
  const int m0 = by * 64, n0 = bx * 128;
  const int lane = tid & 63, wid = tid >> 6;
  const int wm = wid & 1, wn = wid >> 1;
  const int l15 = lane & 15, l4 = lane >> 4;
  const int ar = tid >> 3;            // staging row base 0..31
  const int cb = (tid & 7) << 4;      // staging col byte 0..112
  const char* Abase = (const char*)A;

  // per-lane W row pointers for this warp's 4 nf fragments
  const u16* wrow[4];
  #pragma unroll
  for (int nf = 0; nf < 4; ++nf)
    wrow[nf] = W + (size_t)(n0 + wn * 64 + nf * 16 + l15) * RS + (l4 << 3);

  f32x4 acc[2][4];
  #pragma unroll
  for (int i = 0; i < 2; ++i)
    #pragma unroll
    for (int j = 0; j < 4; ++j) acc[i][j] = (f32x4){0.f, 0.f, 0.f, 0.f};

  auto stageA = [&](int buf, int kt){
    #pragma unroll
    for (int j = 0; j < 2; ++j){
      int r = ar + j * 32;
      const char* src = Abase + (size_t)(m0 + r) * (RS * 2) + (size_t)kt * 128 + (cb ^ ((r & 7) << 4));
      gload16(src, (char*)&ldsA[buf][0] + j * 4096 + wid * 1024);
    }
  };

  auto loadW = [&](int kt, short8 (&w)[8]){
    #pragma unroll
    for (int nf = 0; nf < 4; ++nf){
      #pragma unroll
      for (int ks = 0; ks < 2; ++ks){
        const u16* p = wrow[nf] + (size_t)kt * 64 + ks * 32;
        asm volatile("global_load_dwordx4 %0, %1, off"
                     : "=&v"(w[nf * 2 + ks]) : "v"(p));
      }
    }
  };

  auto consume = [&](int slot, const short8 (&w)[8]){
    #pragma unroll
    for (int ks = 0; ks < 2; ++ks){
      short8 af[2];
      #pragma unroll
      for (int mf = 0; mf < 2; ++mf){
        int r = wm * 32 + mf * 16 + l15;
        int c = (ks * 64 + (l4 << 4)) ^ ((r & 7) << 4);
        af[mf] = *(const short8*)((const char*)&ldsA[slot][0] + r * 128 + c);
      }
      #pragma unroll
      for (int mf = 0; mf < 2; ++mf)
        #pragma unroll
        for (int nf = 0; nf < 4; ++nf)
          acc[mf][nf] = __builtin_amdgcn_mfma_f32_16x16x32_bf16(af[mf], w[nf * 2 + ks], acc[mf][nf], 0, 0, 0);
    }
  };

  const int NT = K / 64;              // even for both K0 (34) and K1 (64)
  short8 wA[8], wB[8];
  stageA(0, 0);
  stageA(1, 1);
  loadW(0, wA);                        // 12 vmem ops in flight

  #pragma unroll 1
  for (int kt = 0; kt < NT; kt += 2){
    // ---- even step: consume wA ----
    asm volatile("s_barrier" ::: "memory");
    if (kt + 2 < NT) stageA((kt + 2) % 3, kt + 2);
    if (kt + 1 < NT) loadW(kt + 1, wB);
    if (kt + 2 < NT)      asm volatile("s_waitcnt vmcnt(10)" ::: "memory");
    else if (kt + 1 < NT) asm volatile("s_waitcnt vmcnt(8)" ::: "memory");
    else                  asm volatile("s_waitcnt vmcnt(0)" ::: "memory");
    __builtin_amdgcn_sched_barrier(0);
    consume(kt % 3, wA);
    __builtin_amdgcn_sched_barrier(0);
    // ---- odd step: consume wB ----
    const int k2 = kt + 1;
    asm volatile("s_barrier" ::: "memory");
    if (k2 + 2 < NT) stageA((k2 + 2) % 3, k2 + 2);
    if (k2 + 1 < NT) loadW(k2 + 1, wA);
    if (k2 + 2 < NT)      asm volatile("s_waitcnt vmcnt(10)" ::: "memory");
    else if (k2 + 1 < NT) asm volatile("s_waitcnt vmcnt(8)" ::: "memory");
    else                  asm volatile("s_waitcnt vmcnt(0)" ::: "memory");
    __builtin_amdgcn_sched_barrier(0);
    consume(k2 % 3, wB);
    __builtin_amdgcn_sched_barrier(0);
  }

  // epilogue: lane&15 = unit-in-group, nf = gate, rows = m
  const int u = (n0 >> 2) + wn * 16 + l15;
  float bg[4];
  #pragma unroll
  for (int nf = 0; nf < 4; ++nf) bg[nf] = bias[n0 + wn * 64 + nf * 16 + l15];
  #pragma unroll
  for (int mf = 0; mf < 2; ++mf){
    const int mb = m0 + wm * 32 + mf * 16 + (l4 << 2);
    #pragma unroll
    for (int reg = 0; reg < 4; ++reg){
      const int m = mb + reg;
      float gi = acc[mf][0][reg] + bg[0];
      float gf = acc[mf][1][reg] + bg[1];
      float gg = acc[mf][2][reg] + bg[2];
      float go = acc[mf][3][reg] + bg[3];
      float iv = sigm(gi), fv = sigm(gf), ov = sigm(go);
      float gv = tanh_f(gg);
      float co = c_in[(size_t)m * ci_rs + u];
      float cn = fv * co + iv * gv;
      float hn = ov * tanh_f(cn);
      c_out[(size_t)m * co_rs + u] = cn;
      u16 hb = f2b(hn);
      h0o[(size_t)m * h0_rs + u] = hb;
      if (h1o) h1o[(size_t)m * h1_rs + u] = hb;
    }
  }
}

// ---------------- output projection: 1 block per batch row ----------------
__global__ __launch_bounds__(256) void proj_step(const u16* __restrict__ h1b, // stride RS1
                                                 const u16* __restrict__ WoTb,
                                                 const float* __restrict__ bout,
                                                 const float* __restrict__ p,
                                                 float* __restrict__ out_pre, int t,
                                                 u16* __restrict__ A0w){
  __shared__ __align__(16) u16 hl[2048];   // 4 KB h1 row
  __shared__ float part[2][128];
  const int b = blockIdx.x;
  const int tid = threadIdx.x;
  *(short8*)&hl[tid * 8] = *(const short8*)(h1b + (size_t)b * RS1 + tid * 8);
  __syncthreads();
  const int n = tid & 127;
  const int kc = tid >> 7;
  float acc = 0.0f;
  if (n < 96){
    const u16* wrow = WoTb + (size_t)n * 2048 + kc * 1024;
    const u16* hrow = hl + kc * 1024;
    for (int k = 0; k < 1024; k += 8){
      uint4 wv = *(const uint4*)(wrow + k);
      uint4 hv = *(const uint4*)(hrow + k);
      acc += blo(wv.x) * blo(hv.x) + bhi(wv.x) * bhi(hv.x);
      acc += blo(wv.y) * blo(hv.y) + bhi(wv.y) * bhi(hv.y);
      acc += blo(wv.z) * blo(hv.z) + bhi(wv.z) * bhi(hv.z);
      acc += blo(wv.w) * blo(hv.w) + bhi(wv.w) * bhi(hv.w);
    }
  }
  part[kc][n] = acc;
  __syncthreads();
  if (tid < 96){
    float s = part[0][tid] + part[1][tid] + bout[tid];
    s += (t == 0) ? p[(size_t)b * 96 + tid]
                  : out_pre[((size_t)b * 50 + (t - 1)) * 96 + tid];
    out_pre[((size_t)b * 50 + t) * 96 + tid] = s;
    A0w[(size_t)b * K0 + tid] = f2b(s);
  }
}

// ---------------- launcher ----------------
extern "C" void kernel_launch(void* const* d_in, const int* in_sizes, int n_in,
                              void* d_out, int out_size, void* d_ws, size_t ws_size,
                              hipStream_t stream){
  const float* hs   = (const float*)d_in[0];
  const float* cs   = (const float*)d_in[1];
  const float* gts  = (const float*)d_in[2];
  const float* p    = (const float*)d_in[4];
  const float* wih0 = (const float*)d_in[6];
  const float* whh0 = (const float*)d_in[7];
  const float* bih0 = (const float*)d_in[8];
  const float* bhh0 = (const float*)d_in[9];
  const float* wih1 = (const float*)d_in[10];
  const float* whh1 = (const float*)d_in[11];
  const float* bih1 = (const float*)d_in[12];
  const float* bhh1 = (const float*)d_in[13];
  const float* wout = (const float*)d_in[14];
  const float* bout = (const float*)d_in[15];

  char* w = (char*)d_ws;
  auto take = [&](size_t bytes) -> char* {
    char* r = w; w += (bytes + 255) & ~(size_t)255; return r;
  };
  u16*  W0    = (u16*)take((size_t)G4 * K0 * 2);
  u16*  W1    = (u16*)take((size_t)G4 * RS1 * 2);
  float* bias0 = (float*)take((size_t)G4 * 4);
  float* bias1 = (float*)take((size_t)G4 * 4);
  u16*  A0    = (u16*)take((size_t)2 * NB * K0 * 2);
  u16*  A1    = (u16*)take((size_t)2 * NB * RS1 * 2);
  float* c0    = (float*)take((size_t)NB * CS * 4);
  u16*  WoTb  = (u16*)take((size_t)96 * HID2 * 2);
  if ((size_t)(w - (char*)d_ws) > ws_size) return;

  const size_t A0sz = (size_t)NB * K0;
  const size_t A1sz = (size_t)NB * RS1;
  float* out_pre  = (float*)d_out;                    // [B][50][96]
  float* out_prec = out_pre + (size_t)NB * 50 * 96;   // [B][50][2048]

  prep_w0<<<dim3(2, G4), 256, 0, stream>>>(wih0, whh0, bih0, bhh0, W0, bias0);
  prep_w1<<<dim3(2, G4), 256, 0, stream>>>(wih1, whh1, bih1, bhh1, W1, bias1);
  prep_wout<<<768, 256, 0, stream>>>(wout, WoTb);
  prep_state<<<512, 256, 0, stream>>>(hs, cs, gts, A0, A1, c0, out_prec);
  prep_x<<<128, 256, 0, stream>>>(p, A0, A0 + A0sz);

  for (int t = 0; t < 50; ++t){
    u16* A0r = A0 + (size_t)(t & 1) * A0sz;
    u16* A0w = A0 + (size_t)((t + 1) & 1) * A0sz;
    u16* A1r = A1 + (size_t)(t & 1) * A1sz;
    u16* A1w = A1 + (size_t)((t + 1) & 1) * A1sz;

    // layer 0: reads A0r=[x|pad|h0], writes h0n -> A1r cols 0.. and A0w cols 128..
    gemm_cell<K0, K0><<<256, 256, 0, stream>>>(A0r, W0, bias0,
        c0, CS, c0, CS,
        A1r, RS1, A0w + 128, K0);

    // layer 1: reads A1r=[h0n|h1]; c1 state lives in out_prec slices
    const float* c1in = out_prec + (size_t)(t ? t - 1 : 0) * HID2;
    gemm_cell<K1, RS1><<<256, 256, 0, stream>>>(A1r, W1, bias1,
        c1in, C1RS, out_prec + (size_t)t * HID2, C1RS,
        A1w + HID2, RS1, (u16*)nullptr, 0);

    // projection: pre = h1n @ Wout + bias_out + prev ; writes next x
    proj_step<<<256, 256, 0, stream>>>(A1w + HID2, WoTb, bout, p, out_pre, t, A0w);
  }
}

// Round 6
// 4349.526 us; speedup vs baseline: 1.3926x; 1.3926x over previous
//
#include <hip/hip_runtime.h>

typedef unsigned short u16;
typedef unsigned int u32;
typedef __attribute__((ext_vector_type(8))) short short8;
typedef __attribute__((ext_vector_type(4))) float f32x4;
typedef float __attribute__((ext_vector_type(4))) f4;

#define NB 256
#define HID2 2048
#define G4 8192
#define K0 2176
#define K1 4096
#define RS1 4160          // padded row stride (elems) for K1-dim buffers
#define CS 2080           // padded c0 row stride (floats)
#define C1RS (50 * HID2)  // c1 state lives in out_prec slices

__device__ __forceinline__ u16 f2b(float f){
  union { float f; u32 u; } v; v.f = f;
  u32 u = v.u;
  u32 r = (u >> 16) & 1u;
  u = u + 0x7fffu + r;
  return (u16)(u >> 16);
}
__device__ __forceinline__ float b2f(u16 h){
  union { u32 u; float f; } v; v.u = ((u32)h) << 16;
  return v.f;
}
__device__ __forceinline__ float blo(u32 a){
  union { u32 u; float f; } v; v.u = a << 16; return v.f;
}
__device__ __forceinline__ float bhi(u32 a){
  union { u32 u; float f; } v; v.u = a & 0xffff0000u; return v.f;
}
__device__ __forceinline__ float sigm(float x){ return 1.0f/(1.0f + __expf(-x)); }
__device__ __forceinline__ float tanh_f(float x){ return 1.0f - 2.0f/(1.0f + __expf(2.0f*x)); }

__device__ __forceinline__ void gload16(const void* g, void* l){
  __builtin_amdgcn_global_load_lds(
      (const __attribute__((address_space(1))) unsigned int*)g,
      (__attribute__((address_space(3))) unsigned int*)l,
      16, 0, 0);
}

// ---------------- prep kernels (non-temporal input reads: keep L3 for weights) ----

__global__ void prep_w0(const float* __restrict__ wih, const float* __restrict__ whh,
                        const float* __restrict__ bih, const float* __restrict__ bhh,
                        u16* __restrict__ W0, float* __restrict__ bias0){
  int n = blockIdx.y;
  int k8 = (blockIdx.x * 256 + threadIdx.x) * 8;
  if (k8 >= K0) return;
  int u = ((n >> 6) << 4) | (n & 15);
  int gate = (n >> 4) & 3;
  int r = gate * HID2 + u;
  float v[8];
  if (k8 < 96){
    f4 a = __builtin_nontemporal_load((const f4*)(wih + (size_t)r * 96 + k8));
    f4 b = __builtin_nontemporal_load((const f4*)(wih + (size_t)r * 96 + k8 + 4));
    v[0]=a[0]; v[1]=a[1]; v[2]=a[2]; v[3]=a[3]; v[4]=b[0]; v[5]=b[1]; v[6]=b[2]; v[7]=b[3];
  } else if (k8 < 128){
    #pragma unroll
    for (int j = 0; j < 8; ++j) v[j] = 0.0f;
  } else {
    f4 a = __builtin_nontemporal_load((const f4*)(whh + (size_t)r * HID2 + (k8 - 128)));
    f4 b = __builtin_nontemporal_load((const f4*)(whh + (size_t)r * HID2 + (k8 - 128) + 4));
    v[0]=a[0]; v[1]=a[1]; v[2]=a[2]; v[3]=a[3]; v[4]=b[0]; v[5]=b[1]; v[6]=b[2]; v[7]=b[3];
  }
  short8 o;
  #pragma unroll
  for (int j = 0; j < 8; ++j) o[j] = (short)f2b(v[j]);
  *(short8*)(W0 + (size_t)n * K0 + k8) = o;
  if (k8 == 0) bias0[n] = bih[r] + bhh[r];
}

__global__ void prep_w1(const float* __restrict__ wih, const float* __restrict__ whh,
                        const float* __restrict__ bih, const float* __restrict__ bhh,
                        u16* __restrict__ W1, float* __restrict__ bias1){
  int n = blockIdx.y;
  int k8 = (blockIdx.x * 256 + threadIdx.x) * 8;
  int u = ((n >> 6) << 4) | (n & 15);
  int gate = (n >> 4) & 3;
  int r = gate * HID2 + u;
  const float* src = (k8 < HID2) ? (wih + (size_t)r * HID2 + k8)
                                 : (whh + (size_t)r * HID2 + (k8 - HID2));
  f4 a = __builtin_nontemporal_load((const f4*)src);
  f4 b = __builtin_nontemporal_load((const f4*)(src + 4));
  short8 o;
  o[0]=(short)f2b(a[0]); o[1]=(short)f2b(a[1]); o[2]=(short)f2b(a[2]); o[3]=(short)f2b(a[3]);
  o[4]=(short)f2b(b[0]); o[5]=(short)f2b(b[1]); o[6]=(short)f2b(b[2]); o[7]=(short)f2b(b[3]);
  *(short8*)(W1 + (size_t)n * RS1 + k8) = o;
  if (k8 == 0) bias1[n] = bih[r] + bhh[r];
}

__global__ void prep_wout(const float* __restrict__ wout, u16* __restrict__ WoTb){
  int id = blockIdx.x * 256 + threadIdx.x;   // 96*2048
  int n = id >> 11, k = id & 2047;
  WoTb[(size_t)n * 2048 + k] = f2b(__builtin_nontemporal_load(wout + (size_t)k * 96 + n));
}

__global__ void prep_state(const float* __restrict__ hs, const float* __restrict__ cs,
                           const float* __restrict__ gts, u16* __restrict__ A0_0,
                           u16* __restrict__ A1_0, float* __restrict__ c0,
                           float* __restrict__ c1prec){
  int id = blockIdx.x * 256 + threadIdx.x;   // 256*512 threads, 4 elems each
  int b = id >> 9;
  int j = (id & 511) << 2;
  const float* hp = hs + (size_t)b * 49 * HID2 + j;
  const float* cp = cs + (size_t)b * 49 * HID2 + j;
  float sh[4] = {0,0,0,0}, sc[4] = {0,0,0,0};
  for (int t = 0; t < 49; ++t){
    f4 hv = __builtin_nontemporal_load((const f4*)(hp + (size_t)t * HID2));
    f4 cv = __builtin_nontemporal_load((const f4*)(cp + (size_t)t * HID2));
    sh[0]+=hv[0]; sh[1]+=hv[1]; sh[2]+=hv[2]; sh[3]+=hv[3];
    sc[0]+=cv[0]; sc[1]+=cv[1]; sc[2]+=cv[2]; sc[3]+=cv[3];
  }
  f4 gv = __builtin_nontemporal_load((const f4*)(gts + (size_t)b * HID2 + j));
  #pragma unroll
  for (int q = 0; q < 4; ++q){
    float cm = sc[q] / 49.0f;
    c0[(size_t)b * CS + j + q] = cm;
    __builtin_nontemporal_store(cm, c1prec + (size_t)b * C1RS + j + q);
    A0_0[(size_t)b * K0 + 128 + j + q] = f2b(sh[q] / 49.0f);
    A1_0[(size_t)b * RS1 + HID2 + j + q] = f2b((sh[q] + gv[q]) / 50.0f);
  }
}

__global__ void prep_x(const float* __restrict__ p, u16* __restrict__ A0_0,
                       u16* __restrict__ A0_1){
  int id = blockIdx.x * 256 + threadIdx.x;  // 256*128
  int b = id >> 7, j = id & 127;
  u16 v = (j < 96) ? f2b(p[(size_t)b * 96 + j]) : (u16)0;
  A0_0[(size_t)b * K0 + j] = v;
  if (j >= 96) A0_1[(size_t)b * K0 + j] = 0;
}

// ---------------- fused GEMM + LSTM cell ----------------
// 64x64 tiles, grid 512, LDS 48KB -> 3 blocks/CU (12 waves): three
// independent barrier-groups per CU so vmcnt stalls overlap (the 1-block/CU
// lockstep was the r1-r5 wall). Wave w owns rows w*16..+15 x all 64 cols
// (= one full 16-unit x 4-gate group -> fused epilogue unchanged).
template<int K, int RS, bool NTC>
__global__ __launch_bounds__(256, 3) void gemm_cell(
    const u16* __restrict__ A, const u16* __restrict__ W, const float* __restrict__ bias,
    const float* __restrict__ c_in, int ci_rs, float* __restrict__ c_out, int co_rs,
    u16* __restrict__ h0o, int h0_rs, u16* __restrict__ h1o, int h1_rs)
{
  __shared__ u16 ldsA[3][64 * 64];    // 8KB each
  __shared__ u16 ldsB[3][64 * 64];    // 8KB each (total 48KB)
  const int tid = threadIdx.x;
  const int id = blockIdx.x;
  // p = n-panel (0..127), my = m-tile (0..3); the 4 m-tiles of a panel have
  // ids differing by 128 -> same id%8 -> same XCD (W panel L2 reuse).
  const int p  = ((id & 7) << 4) | ((id >> 3) & 15);
  const int my = id >> 7;
  const int m0 = my * 64, n0 = p * 64;
  const int lane = tid & 63, wid = tid >> 6;
  const int l15 = lane & 15, l4 = lane >> 4;
  const int ar = tid >> 3;            // staging row base 0..31
  const int cb = (tid & 7) << 4;      // staging col byte 0..112
  const char* Abase = (const char*)A;
  const char* Wbase = (const char*)W;

  f32x4 acc[4];
  #pragma unroll
  for (int j = 0; j < 4; ++j) acc[j] = (f32x4){0.f, 0.f, 0.f, 0.f};

  auto stage = [&](int buf, int kt){
    const size_t kofs = (size_t)kt * 128;
    #pragma unroll
    for (int j = 0; j < 2; ++j){
      int r = ar + j * 32;
      const char* srcA = Abase + (size_t)(m0 + r) * (RS * 2) + kofs + (cb ^ ((r & 7) << 4));
      gload16(srcA, (char*)&ldsA[buf][0] + j * 4096 + wid * 1024);
      const char* srcW = Wbase + (size_t)(n0 + r) * (RS * 2) + kofs + (cb ^ ((r & 7) << 4));
      gload16(srcW, (char*)&ldsB[buf][0] + j * 4096 + wid * 1024);
    }
  };

  auto consume = [&](int slot){
    #pragma unroll
    for (int ks = 0; ks < 2; ++ks){
      short8 af;
      {
        int r = wid * 16 + l15;
        int c = (ks * 64 + (l4 << 4)) ^ ((r & 7) << 4);
        af = *(const short8*)((const char*)&ldsA[slot][0] + r * 128 + c);
      }
      #pragma unroll
      for (int nf = 0; nf < 4; ++nf){
        int r = nf * 16 + l15;
        int c = (ks * 64 + (l4 << 4)) ^ ((r & 7) << 4);
        short8 wf = *(const short8*)((const char*)&ldsB[slot][0] + r * 128 + c);
        acc[nf] = __builtin_amdgcn_mfma_f32_16x16x32_bf16(af, wf, acc[nf], 0, 0, 0);
      }
    }
  };

  const int NT = K / 64;
  stage(0, 0);
  stage(1, 1);
  // depth-2 prefetch: stage kt+2 each iter; wait only for kt's own 4 loads.
  for (int kt = 0; kt < NT; ++kt){
    const int cur = kt % 3;
    if (kt + 2 < NT){
      stage((kt + 2) % 3, kt + 2);
      asm volatile("s_waitcnt vmcnt(8)" ::: "memory");
    } else if (kt + 1 < NT){
      asm volatile("s_waitcnt vmcnt(4)" ::: "memory");
    } else {
      asm volatile("s_waitcnt vmcnt(0)" ::: "memory");
    }
    __builtin_amdgcn_s_barrier();
    consume(cur);
    __builtin_amdgcn_s_barrier();   // all reads of buf done before its re-stage
  }

  // epilogue: lane&15 = unit-in-group, nf = gate
  const int u = (n0 >> 2) + l15;     // p*16 + l15
  float bg[4];
  #pragma unroll
  for (int nf = 0; nf < 4; ++nf) bg[nf] = bias[n0 + nf * 16 + l15];
  const int mb = m0 + wid * 16 + (l4 << 2);
  #pragma unroll
  for (int reg = 0; reg < 4; ++reg){
    const int m = mb + reg;
    float gi = acc[0][reg] + bg[0];
    float gf = acc[1][reg] + bg[1];
    float gg = acc[2][reg] + bg[2];
    float go = acc[3][reg] + bg[3];
    float iv = sigm(gi), fv = sigm(gf), ov = sigm(go);
    float gv = tanh_f(gg);
    float co = c_in[(size_t)m * ci_rs + u];
    float cn = fv * co + iv * gv;
    float hn = ov * tanh_f(cn);
    if (NTC) __builtin_nontemporal_store(cn, c_out + (size_t)m * co_rs + u);
    else     c_out[(size_t)m * co_rs + u] = cn;
    u16 hb = f2b(hn);
    h0o[(size_t)m * h0_rs + u] = hb;
    if (h1o) h1o[(size_t)m * h1_rs + u] = hb;
  }
}

// ---------------- output projection: 1 block per batch row ----------------
__global__ __launch_bounds__(256) void proj_step(const u16* __restrict__ h1b, // stride RS1
                                                 const u16* __restrict__ WoTb,
                                                 const float* __restrict__ bout,
                                                 const float* __restrict__ p,
                                                 float* __restrict__ out_pre, int t,
                                                 u16* __restrict__ A0w){
  __shared__ __align__(16) u16 hl[2048];   // 4 KB h1 row
  __shared__ float part[2][128];
  const int b = blockIdx.x;
  const int tid = threadIdx.x;
  *(short8*)&hl[tid * 8] = *(const short8*)(h1b + (size_t)b * RS1 + tid * 8);
  __syncthreads();
  const int n = tid & 127;
  const int kc = tid >> 7;
  float acc = 0.0f;
  if (n < 96){
    const u16* wrow = WoTb + (size_t)n * 2048 + kc * 1024;
    const u16* hrow = hl + kc * 1024;
    for (int k = 0; k < 1024; k += 8){
      uint4 wv = *(const uint4*)(wrow + k);
      uint4 hv = *(const uint4*)(hrow + k);
      acc += blo(wv.x) * blo(hv.x) + bhi(wv.x) * bhi(hv.x);
      acc += blo(wv.y) * blo(hv.y) + bhi(wv.y) * bhi(hv.y);
      acc += blo(wv.z) * blo(hv.z) + bhi(wv.z) * bhi(hv.z);
      acc += blo(wv.w) * blo(hv.w) + bhi(wv.w) * bhi(hv.w);
    }
  }
  part[kc][n] = acc;
  __syncthreads();
  if (tid < 96){
    float s = part[0][tid] + part[1][tid] + bout[tid];
    s += (t == 0) ? p[(size_t)b * 96 + tid]
                  : out_pre[((size_t)b * 50 + (t - 1)) * 96 + tid];
    __builtin_nontemporal_store(s, out_pre + ((size_t)b * 50 + t) * 96 + tid);
    A0w[(size_t)b * K0 + tid] = f2b(s);
  }
}

// ---------------- launcher ----------------
extern "C" void kernel_launch(void* const* d_in, const int* in_sizes, int n_in,
                              void* d_out, int out_size, void* d_ws, size_t ws_size,
                              hipStream_t stream){
  const float* hs   = (const float*)d_in[0];
  const float* cs   = (const float*)d_in[1];
  const float* gts  = (const float*)d_in[2];
  const float* p    = (const float*)d_in[4];
  const float* wih0 = (const float*)d_in[6];
  const float* whh0 = (const float*)d_in[7];
  const float* bih0 = (const float*)d_in[8];
  const float* bhh0 = (const float*)d_in[9];
  const float* wih1 = (const float*)d_in[10];
  const float* whh1 = (const float*)d_in[11];
  const float* bih1 = (const float*)d_in[12];
  const float* bhh1 = (const float*)d_in[13];
  const float* wout = (const float*)d_in[14];
  const float* bout = (const float*)d_in[15];

  char* w = (char*)d_ws;
  auto take = [&](size_t bytes) -> char* {
    char* r = w; w += (bytes + 255) & ~(size_t)255; return r;
  };
  u16*  W0    = (u16*)take((size_t)G4 * K0 * 2);
  u16*  W1    = (u16*)take((size_t)G4 * RS1 * 2);
  float* bias0 = (float*)take((size_t)G4 * 4);
  float* bias1 = (float*)take((size_t)G4 * 4);
  u16*  A0    = (u16*)take((size_t)2 * NB * K0 * 2);
  u16*  A1    = (u16*)take((size_t)2 * NB * RS1 * 2);
  float* c0    = (float*)take((size_t)NB * CS * 4);
  u16*  WoTb  = (u16*)take((size_t)96 * HID2 * 2);
  if ((size_t)(w - (char*)d_ws) > ws_size) return;

  const size_t A0sz = (size_t)NB * K0;
  const size_t A1sz = (size_t)NB * RS1;
  float* out_pre  = (float*)d_out;                    // [B][50][96]
  float* out_prec = out_pre + (size_t)NB * 50 * 96;   // [B][50][2048]

  prep_w0<<<dim3(2, G4), 256, 0, stream>>>(wih0, whh0, bih0, bhh0, W0, bias0);
  prep_w1<<<dim3(2, G4), 256, 0, stream>>>(wih1, whh1, bih1, bhh1, W1, bias1);
  prep_wout<<<768, 256, 0, stream>>>(wout, WoTb);
  prep_state<<<512, 256, 0, stream>>>(hs, cs, gts, A0, A1, c0, out_prec);
  prep_x<<<128, 256, 0, stream>>>(p, A0, A0 + A0sz);

  for (int t = 0; t < 50; ++t){
    u16* A0r = A0 + (size_t)(t & 1) * A0sz;
    u16* A0w = A0 + (size_t)((t + 1) & 1) * A0sz;
    u16* A1r = A1 + (size_t)(t & 1) * A1sz;
    u16* A1w = A1 + (size_t)((t + 1) & 1) * A1sz;

    // layer 0: reads A0r=[x|pad|h0], writes h0n -> A1r cols 0.. and A0w cols 128..
    gemm_cell<K0, K0, false><<<512, 256, 0, stream>>>(A0r, W0, bias0,
        c0, CS, c0, CS,
        A1r, RS1, A0w + 128, K0);

    // layer 1: reads A1r=[h0n|h1]; c1 state lives in out_prec slices
    const float* c1in = out_prec + (size_t)(t ? t - 1 : 0) * HID2;
    gemm_cell<K1, RS1, true><<<512, 256, 0, stream>>>(A1r, W1, bias1,
        c1in, C1RS, out_prec + (size_t)t * HID2, C1RS,
        A1w + HID2, RS1, (u16*)nullptr, 0);

    // projection: pre = h1n @ Wout + bias_out + prev ; writes next x
    proj_step<<<256, 256, 0, stream>>>(A1w + HID2, WoTb, bout, p, out_pre, t, A0w);
  }
}

// Round 8
// 4051.029 us; speedup vs baseline: 1.4952x; 1.0737x over previous
//
#include <hip/hip_runtime.h>

typedef unsigned short u16;
typedef unsigned int u32;
typedef __attribute__((ext_vector_type(8))) short short8;
typedef __attribute__((ext_vector_type(4))) float f32x4;
typedef float __attribute__((ext_vector_type(4))) f4;

#define NB 256
#define HID2 2048
#define G4 8192
#define K0 2176
#define K1 4096
#define RS1 4160          // padded row stride (elems) for K1-dim buffers
#define CS 2080           // padded c0 row stride (floats)
#define C1RS (50 * HID2)  // c1 state lives in out_prec slices

__device__ __forceinline__ u16 f2b(float f){
  union { float f; u32 u; } v; v.f = f;
  u32 u = v.u;
  u32 r = (u >> 16) & 1u;
  u = u + 0x7fffu + r;
  return (u16)(u >> 16);
}
__device__ __forceinline__ float b2f(u16 h){
  union { u32 u; float f; } v; v.u = ((u32)h) << 16;
  return v.f;
}
__device__ __forceinline__ float blo(u32 a){
  union { u32 u; float f; } v; v.u = a << 16; return v.f;
}
__device__ __forceinline__ float bhi(u32 a){
  union { u32 u; float f; } v; v.u = a & 0xffff0000u; return v.f;
}
__device__ __forceinline__ float sigm(float x){ return 1.0f/(1.0f + __expf(-x)); }
__device__ __forceinline__ float tanh_f(float x){ return 1.0f - 2.0f/(1.0f + __expf(2.0f*x)); }

__device__ __forceinline__ void gload16(const void* g, void* l){
  __builtin_amdgcn_global_load_lds(
      (const __attribute__((address_space(1))) unsigned int*)g,
      (__attribute__((address_space(3))) unsigned int*)l,
      16, 0, 0);
}

// ---------------- prep kernels (non-temporal input reads: keep L3 for weights) ----

__global__ void prep_w0(const float* __restrict__ wih, const float* __restrict__ whh,
                        const float* __restrict__ bih, const float* __restrict__ bhh,
                        u16* __restrict__ W0, float* __restrict__ bias0){
  int n = blockIdx.y;
  int k8 = (blockIdx.x * 256 + threadIdx.x) * 8;
  if (k8 >= K0) return;
  int u = ((n >> 6) << 4) | (n & 15);
  int gate = (n >> 4) & 3;
  int r = gate * HID2 + u;
  float v[8];
  if (k8 < 96){
    f4 a = __builtin_nontemporal_load((const f4*)(wih + (size_t)r * 96 + k8));
    f4 b = __builtin_nontemporal_load((const f4*)(wih + (size_t)r * 96 + k8 + 4));
    v[0]=a[0]; v[1]=a[1]; v[2]=a[2]; v[3]=a[3]; v[4]=b[0]; v[5]=b[1]; v[6]=b[2]; v[7]=b[3];
  } else if (k8 < 128){
    #pragma unroll
    for (int j = 0; j < 8; ++j) v[j] = 0.0f;
  } else {
    f4 a = __builtin_nontemporal_load((const f4*)(whh + (size_t)r * HID2 + (k8 - 128)));
    f4 b = __builtin_nontemporal_load((const f4*)(whh + (size_t)r * HID2 + (k8 - 128) + 4));
    v[0]=a[0]; v[1]=a[1]; v[2]=a[2]; v[3]=a[3]; v[4]=b[0]; v[5]=b[1]; v[6]=b[2]; v[7]=b[3];
  }
  short8 o;
  #pragma unroll
  for (int j = 0; j < 8; ++j) o[j] = (short)f2b(v[j]);
  *(short8*)(W0 + (size_t)n * K0 + k8) = o;
  if (k8 == 0) bias0[n] = bih[r] + bhh[r];
}

__global__ void prep_w1(const float* __restrict__ wih, const float* __restrict__ whh,
                        const float* __restrict__ bih, const float* __restrict__ bhh,
                        u16* __restrict__ W1, float* __restrict__ bias1){
  int n = blockIdx.y;
  int k8 = (blockIdx.x * 256 + threadIdx.x) * 8;
  int u = ((n >> 6) << 4) | (n & 15);
  int gate = (n >> 4) & 3;
  int r = gate * HID2 + u;
  const float* src = (k8 < HID2) ? (wih + (size_t)r * HID2 + k8)
                                 : (whh + (size_t)r * HID2 + (k8 - HID2));
  f4 a = __builtin_nontemporal_load((const f4*)src);
  f4 b = __builtin_nontemporal_load((const f4*)(src + 4));
  short8 o;
  o[0]=(short)f2b(a[0]); o[1]=(short)f2b(a[1]); o[2]=(short)f2b(a[2]); o[3]=(short)f2b(a[3]);
  o[4]=(short)f2b(b[0]); o[5]=(short)f2b(b[1]); o[6]=(short)f2b(b[2]); o[7]=(short)f2b(b[3]);
  *(short8*)(W1 + (size_t)n * RS1 + k8) = o;
  if (k8 == 0) bias1[n] = bih[r] + bhh[r];
}

__global__ void prep_wout(const float* __restrict__ wout, u16* __restrict__ WoTb){
  int id = blockIdx.x * 256 + threadIdx.x;   // 96*2048
  int n = id >> 11, k = id & 2047;
  WoTb[(size_t)n * 2048 + k] = f2b(__builtin_nontemporal_load(wout + (size_t)k * 96 + n));
}

__global__ void prep_state(const float* __restrict__ hs, const float* __restrict__ cs,
                           const float* __restrict__ gts, u16* __restrict__ A0_0,
                           u16* __restrict__ A1_0, float* __restrict__ c0,
                           float* __restrict__ c1prec){
  int id = blockIdx.x * 256 + threadIdx.x;   // 256*512 threads, 4 elems each
  int b = id >> 9;
  int j = (id & 511) << 2;
  const float* hp = hs + (size_t)b * 49 * HID2 + j;
  const float* cp = cs + (size_t)b * 49 * HID2 + j;
  float sh[4] = {0,0,0,0}, sc[4] = {0,0,0,0};
  for (int t = 0; t < 49; ++t){
    f4 hv = __builtin_nontemporal_load((const f4*)(hp + (size_t)t * HID2));
    f4 cv = __builtin_nontemporal_load((const f4*)(cp + (size_t)t * HID2));
    sh[0]+=hv[0]; sh[1]+=hv[1]; sh[2]+=hv[2]; sh[3]+=hv[3];
    sc[0]+=cv[0]; sc[1]+=cv[1]; sc[2]+=cv[2]; sc[3]+=cv[3];
  }
  f4 gv = __builtin_nontemporal_load((const f4*)(gts + (size_t)b * HID2 + j));
  #pragma unroll
  for (int q = 0; q < 4; ++q){
    float cm = sc[q] / 49.0f;
    c0[(size_t)b * CS + j + q] = cm;
    __builtin_nontemporal_store(cm, c1prec + (size_t)b * C1RS + j + q);
    A0_0[(size_t)b * K0 + 128 + j + q] = f2b(sh[q] / 49.0f);
    A1_0[(size_t)b * RS1 + HID2 + j + q] = f2b((sh[q] + gv[q]) / 50.0f);
  }
}

__global__ void prep_x(const float* __restrict__ p, u16* __restrict__ A0_0,
                       u16* __restrict__ A0_1){
  int id = blockIdx.x * 256 + threadIdx.x;  // 256*128
  int b = id >> 7, j = id & 127;
  u16 v = (j < 96) ? f2b(p[(size_t)b * 96 + j]) : (u16)0;
  A0_0[(size_t)b * K0 + j] = v;
  if (j >= 96) A0_1[(size_t)b * K0 + j] = 0;
}

// ---------------- fused GEMM + LSTM cell ----------------
// 64x64 tiles, grid 512, 4 LDS buffers (64KB) -> 2 blocks/CU, 8 waves/CU.
// ONE barrier per K-step: {stage(kt+2); vmcnt(8); s_barrier; consume(kt)}.
//  - barrier AFTER each wave's vmcnt publishes all waves' kt loads (visibility)
//  - overwrite target (kt+2)&3 is >=2 mod 4 away from any wave's live reads
//    (leader blocks at barrier kt+1 until laggard leaves consume(kt)) -> safe
//  - fast waves stage ahead while slow waves consume (r6's trailing barrier
//    forbade exactly this overlap).
template<int K, int RS, bool NTC>
__global__ __launch_bounds__(256, 2) void gemm_cell(
    const u16* __restrict__ A, const u16* __restrict__ W, const float* __restrict__ bias,
    const float* __restrict__ c_in, int ci_rs, float* __restrict__ c_out, int co_rs,
    u16* __restrict__ h0o, int h0_rs, u16* __restrict__ h1o, int h1_rs)
{
  __shared__ u16 ldsA[4][64 * 64];    // 8KB each
  __shared__ u16 ldsB[4][64 * 64];    // 8KB each (total 64KB)
  const int tid = threadIdx.x;
  const int id = blockIdx.x;
  // p = n-panel (0..127), my = m-tile (0..3); the 4 m-tiles of a panel share
  // id%8 -> same XCD (W panel L2/L3 reuse).
  const int p  = ((id & 7) << 4) | ((id >> 3) & 15);
  const int my = id >> 7;
  const int m0 = my * 64, n0 = p * 64;
  const int lane = tid & 63, wid = tid >> 6;
  const int l15 = lane & 15, l4 = lane >> 4;
  const int ar = tid >> 3;            // staging row base 0..31
  const int cb = (tid & 7) << 4;      // staging col byte 0..112
  const char* Abase = (const char*)A;
  const char* Wbase = (const char*)W;

  f32x4 acc[4];
  #pragma unroll
  for (int j = 0; j < 4; ++j) acc[j] = (f32x4){0.f, 0.f, 0.f, 0.f};

  auto stage = [&](int buf, int kt){
    const size_t kofs = (size_t)kt * 128;
    #pragma unroll
    for (int j = 0; j < 2; ++j){
      int r = ar + j * 32;
      const char* srcA = Abase + (size_t)(m0 + r) * (RS * 2) + kofs + (cb ^ ((r & 7) << 4));
      gload16(srcA, (char*)&ldsA[buf][0] + j * 4096 + wid * 1024);
      const char* srcW = Wbase + (size_t)(n0 + r) * (RS * 2) + kofs + (cb ^ ((r & 7) << 4));
      gload16(srcW, (char*)&ldsB[buf][0] + j * 4096 + wid * 1024);
    }
  };

  auto consume = [&](int slot){
    #pragma unroll
    for (int ks = 0; ks < 2; ++ks){
      short8 af;
      {
        int r = wid * 16 + l15;
        int c = (ks * 64 + (l4 << 4)) ^ ((r & 7) << 4);
        af = *(const short8*)((const char*)&ldsA[slot][0] + r * 128 + c);
      }
      #pragma unroll
      for (int nf = 0; nf < 4; ++nf){
        int r = nf * 16 + l15;
        int c = (ks * 64 + (l4 << 4)) ^ ((r & 7) << 4);
        short8 wf = *(const short8*)((const char*)&ldsB[slot][0] + r * 128 + c);
        acc[nf] = __builtin_amdgcn_mfma_f32_16x16x32_bf16(af, wf, acc[nf], 0, 0, 0);
      }
    }
  };

  const int NT = K / 64;
  stage(0, 0);
  stage(1, 1);
  for (int kt = 0; kt < NT; ++kt){
    if (kt + 2 < NT){
      stage((kt + 2) & 3, kt + 2);
      asm volatile("s_waitcnt vmcnt(8)" ::: "memory");   // kt's 4 loads retired
    } else if (kt + 1 < NT){
      asm volatile("s_waitcnt vmcnt(4)" ::: "memory");
    } else {
      asm volatile("s_waitcnt vmcnt(0)" ::: "memory");
    }
    __builtin_amdgcn_sched_barrier(0);
    __builtin_amdgcn_s_barrier();     // publishes every wave's kt loads
    __builtin_amdgcn_s_setprio(1);
    consume(kt & 3);
    __builtin_amdgcn_s_setprio(0);
  }

  // epilogue: lane&15 = unit-in-group, nf = gate
  const int u = (n0 >> 2) + l15;     // p*16 + l15
  float bg[4];
  #pragma unroll
  for (int nf = 0; nf < 4; ++nf) bg[nf] = bias[n0 + nf * 16 + l15];
  const int mb = m0 + wid * 16 + (l4 << 2);
  #pragma unroll
  for (int reg = 0; reg < 4; ++reg){
    const int m = mb + reg;
    float gi = acc[0][reg] + bg[0];
    float gf = acc[1][reg] + bg[1];
    float gg = acc[2][reg] + bg[2];
    float go = acc[3][reg] + bg[3];
    float iv = sigm(gi), fv = sigm(gf), ov = sigm(go);
    float gv = tanh_f(gg);
    float co = c_in[(size_t)m * ci_rs + u];
    float cn = fv * co + iv * gv;
    float hn = ov * tanh_f(cn);
    if (NTC) __builtin_nontemporal_store(cn, c_out + (size_t)m * co_rs + u);
    else     c_out[(size_t)m * co_rs + u] = cn;
    u16 hb = f2b(hn);
    h0o[(size_t)m * h0_rs + u] = hb;
    if (h1o) h1o[(size_t)m * h1_rs + u] = hb;
  }
}

// ---------------- output projection: 1 block per batch row ----------------
__global__ __launch_bounds__(256) void proj_step(const u16* __restrict__ h1b, // stride RS1
                                                 const u16* __restrict__ WoTb,
                                                 const float* __restrict__ bout,
                                                 const float* __restrict__ p,
                                                 float* __restrict__ out_pre, int t,
                                                 u16* __restrict__ A0w){
  __shared__ __align__(16) u16 hl[2048];   // 4 KB h1 row
  __shared__ float part[2][128];
  const int b = blockIdx.x;
  const int tid = threadIdx.x;
  *(short8*)&hl[tid * 8] = *(const short8*)(h1b + (size_t)b * RS1 + tid * 8);
  __syncthreads();
  const int n = tid & 127;
  const int kc = tid >> 7;
  float acc = 0.0f;
  if (n < 96){
    const u16* wrow = WoTb + (size_t)n * 2048 + kc * 1024;
    const u16* hrow = hl + kc * 1024;
    for (int k = 0; k < 1024; k += 8){
      uint4 wv = *(const uint4*)(wrow + k);
      uint4 hv = *(const uint4*)(hrow + k);
      acc += blo(wv.x) * blo(hv.x) + bhi(wv.x) * bhi(hv.x);
      acc += blo(wv.y) * blo(hv.y) + bhi(wv.y) * bhi(hv.y);
      acc += blo(wv.z) * blo(hv.z) + bhi(wv.z) * bhi(hv.z);
      acc += blo(wv.w) * blo(hv.w) + bhi(wv.w) * bhi(hv.w);
    }
  }
  part[kc][n] = acc;
  __syncthreads();
  if (tid < 96){
    float s = part[0][tid] + part[1][tid] + bout[tid];
    s += (t == 0) ? p[(size_t)b * 96 + tid]
                  : out_pre[((size_t)b * 50 + (t - 1)) * 96 + tid];
    __builtin_nontemporal_store(s, out_pre + ((size_t)b * 50 + t) * 96 + tid);
    A0w[(size_t)b * K0 + tid] = f2b(s);
  }
}

// ---------------- launcher ----------------
extern "C" void kernel_launch(void* const* d_in, const int* in_sizes, int n_in,
                              void* d_out, int out_size, void* d_ws, size_t ws_size,
                              hipStream_t stream){
  const float* hs   = (const float*)d_in[0];
  const float* cs   = (const float*)d_in[1];
  const float* gts  = (const float*)d_in[2];
  const float* p    = (const float*)d_in[4];
  const float* wih0 = (const float*)d_in[6];
  const float* whh0 = (const float*)d_in[7];
  const float* bih0 = (const float*)d_in[8];
  const float* bhh0 = (const float*)d_in[9];
  const float* wih1 = (const float*)d_in[10];
  const float* whh1 = (const float*)d_in[11];
  const float* bih1 = (const float*)d_in[12];
  const float* bhh1 = (const float*)d_in[13];
  const float* wout = (const float*)d_in[14];
  const float* bout = (const float*)d_in[15];

  char* w = (char*)d_ws;
  auto take = [&](size_t bytes) -> char* {
    char* r = w; w += (bytes + 255) & ~(size_t)255; return r;
  };
  u16*  W0    = (u16*)take((size_t)G4 * K0 * 2);
  u16*  W1    = (u16*)take((size_t)G4 * RS1 * 2);
  float* bias0 = (float*)take((size_t)G4 * 4);
  float* bias1 = (float*)take((size_t)G4 * 4);
  u16*  A0    = (u16*)take((size_t)2 * NB * K0 * 2);
  u16*  A1    = (u16*)take((size_t)2 * NB * RS1 * 2);
  float* c0    = (float*)take((size_t)NB * CS * 4);
  u16*  WoTb  = (u16*)take((size_t)96 * HID2 * 2);
  if ((size_t)(w - (char*)d_ws) > ws_size) return;

  const size_t A0sz = (size_t)NB * K0;
  const size_t A1sz = (size_t)NB * RS1;
  float* out_pre  = (float*)d_out;                    // [B][50][96]
  float* out_prec = out_pre + (size_t)NB * 50 * 96;   // [B][50][2048]

  prep_w0<<<dim3(2, G4), 256, 0, stream>>>(wih0, whh0, bih0, bhh0, W0, bias0);
  prep_w1<<<dim3(2, G4), 256, 0, stream>>>(wih1, whh1, bih1, bhh1, W1, bias1);
  prep_wout<<<768, 256, 0, stream>>>(wout, WoTb);
  prep_state<<<512, 256, 0, stream>>>(hs, cs, gts, A0, A1, c0, out_prec);
  prep_x<<<128, 256, 0, stream>>>(p, A0, A0 + A0sz);

  for (int t = 0; t < 50; ++t){
    u16* A0r = A0 + (size_t)(t & 1) * A0sz;
    u16* A0w = A0 + (size_t)((t + 1) & 1) * A0sz;
    u16* A1r = A1 + (size_t)(t & 1) * A1sz;
    u16* A1w = A1 + (size_t)((t + 1) & 1) * A1sz;

    // layer 0: reads A0r=[x|pad|h0], writes h0n -> A1r cols 0.. and A0w cols 128..
    gemm_cell<K0, K0, false><<<512, 256, 0, stream>>>(A0r, W0, bias0,
        c0, CS, c0, CS,
        A1r, RS1, A0w + 128, K0);

    // layer 1: reads A1r=[h0n|h1]; c1 state lives in out_prec slices
    const float* c1in = out_prec + (size_t)(t ? t - 1 : 0) * HID2;
    gemm_cell<K1, RS1, true><<<512, 256, 0, stream>>>(A1r, W1, bias1,
        c1in, C1RS, out_prec + (size_t)t * HID2, C1RS,
        A1w + HID2, RS1, (u16*)nullptr, 0);

    // projection: pre = h1n @ Wout + bias_out + prev ; writes next x
    proj_step<<<256, 256, 0, stream>>>(A1w + HID2, WoTb, bout, p, out_pre, t, A0w);
  }
}